// Round 6
// baseline (671.039 us; speedup 1.0000x reference)
//
#include <hip/hip_runtime.h>
#include <hip/hip_bf16.h>
#include <stdint.h>

// VectorQuantization: out[n] = codebook[argmax_k dot(x[n], codebook[k])]
// (L2-normalize is a positive row-scalar -> argmax-invariant -> skipped)
//
// R6: registers-only streaming fp8 GEMM — NO LDS in the hot loop, no k-loop
// barriers. A and B fragments both load global->VGPR (32B/lane, a wave
// consumes 16 full 128B lines per fragment set; 12MB working set is
// L2/L3-resident). Epilogue / coverage / recheck are R4-VERBATIM (validated
// passing): NSPLIT=64 (256 codes/split), explicit (v,i) top-2, MARGIN=3.2
// (=0.05 true scale) flagging + exact fp64 recheck, lowest-index tie-break.
//
// R5 post-mortem: absmax 0.073 == "all rows wrong" statistical signature;
// prime suspect was the 67.5KB static LDS allocation (beyond any validated
// size -> possible silent launch failure -> poisoned partials). This round
// eliminates LDS wholesale rather than re-rolling that die.

typedef float f32x4 __attribute__((ext_vector_type(4)));
typedef int int4v __attribute__((ext_vector_type(4)));
typedef int int8v __attribute__((ext_vector_type(8)));

#define M_ROWS 8192
#define DIM 512
#define K_CODES 16384
#define BM 128
#define NSPLIT 64
#define CPS (K_CODES / NSPLIT)      /* 256 codes per split */
#define NEG_INF (-3.402823466e+38f)
#define MARGIN 3.2f                 /* 0.05 in true sim scale (x64) */
#define CB_SCALE 64.0f
#define N4X (M_ROWS * DIM / 4)
#define N4C (K_CODES * DIM / 4)

// fused fp32 -> e4m3: blocks [0, N4X/256) convert x (scale 1), rest codebook (x64)
// (R4-verbatim)
__global__ void cvt_fp8(const float* __restrict__ x, const float* __restrict__ cb,
                        uint8_t* __restrict__ xd, uint8_t* __restrict__ cd) {
  int i = blockIdx.x * 256 + threadIdx.x;
  const float* src;
  uint8_t* dst;
  float sc;
  if (i < N4X) {
    src = x; dst = xd; sc = 1.0f;
  } else {
    src = cb; dst = cd; sc = CB_SCALE; i -= N4X;
    if (i >= N4C) return;
  }
  const float4 v = reinterpret_cast<const float4*>(src)[i];
  int w = 0;
  w = __builtin_amdgcn_cvt_pk_fp8_f32(v.x * sc, v.y * sc, w, false);
  w = __builtin_amdgcn_cvt_pk_fp8_f32(v.z * sc, v.w * sc, w, true);
  reinterpret_cast<int*>(dst)[i] = w;
}

__device__ __forceinline__ int8v load32(const uint8_t* p) {
  int4v lo = *(const int4v*)p;
  int4v hi = *(const int4v*)(p + 16);
  return __builtin_shufflevector(lo, hi, 0, 1, 2, 3, 4, 5, 6, 7);
}

__global__ __launch_bounds__(256, 2) void vq_argmax(
    const uint8_t* __restrict__ xq, const uint8_t* __restrict__ cq,
    float* __restrict__ pv, int* __restrict__ pi) {
  __shared__ float rv1[2][BM], rv2[2][BM];     // tiny cross-wave merge scratch
  __shared__ int ri1[2][BM], ri2[2][BM];

  const int tid = threadIdx.x;
  const int w = tid >> 6, lane = tid & 63;
  const int wm = w & 1, wn = w >> 1;           // 2x2 wave grid: rows x codes
  const int l15 = lane & 15, quad = lane >> 4;
  const int row0 = blockIdx.x * BM;
  const int split = blockIdx.y;
  const int cbase = split * CPS + wn * 128;    // this wave's 128-code strip

  // per-lane fragment base pointers: 32 contiguous bytes at k = quad*32
  // (identical lane->(m/n,k) mapping to the R4-validated LDS path)
  const uint8_t* abase = xq + (size_t)(row0 + wm * 64 + l15) * DIM + (quad << 5);
  const uint8_t* bbase = cq + (size_t)(cbase + l15) * DIM + (quad << 5);

  float bv1[4][4], bv2[4][4];
  int bi1[4][4], bi2[4][4];
#pragma unroll
  for (int i = 0; i < 4; ++i)
#pragma unroll
    for (int r = 0; r < 4; ++r) {
      bv1[i][r] = NEG_INF; bv2[i][r] = NEG_INF;
      bi1[i][r] = 0x7fffffff; bi2[i][r] = 0x7fffffff;
    }

#pragma unroll
  for (int js = 0; js < 2; ++js) {             // 64 codes per js-step per wave
    f32x4 acc[4][4];
#pragma unroll
    for (int i = 0; i < 4; ++i)
#pragma unroll
      for (int j = 0; j < 4; ++j) acc[i][j] = (f32x4){0.f, 0.f, 0.f, 0.f};

#pragma unroll
    for (int ks = 0; ks < 4; ++ks) {
      int8v A[4], B[4];
#pragma unroll
      for (int i = 0; i < 4; ++i)
        A[i] = load32(abase + (size_t)(i * 16) * DIM + ks * 128);
#pragma unroll
      for (int j = 0; j < 4; ++j)
        B[j] = load32(bbase + (size_t)(js * 64 + j * 16) * DIM + ks * 128);
#pragma unroll
      for (int i = 0; i < 4; ++i)
#pragma unroll
        for (int j = 0; j < 4; ++j)
          acc[i][j] = __builtin_amdgcn_mfma_scale_f32_16x16x128_f8f6f4(
              A[i], B[j], acc[i][j], 0 /*fp8*/, 0 /*fp8*/,
              0, 0x7F7F7F7F /*scaleA=1.0*/, 0, 0x7F7F7F7F /*scaleB=1.0*/);
    }

    // R4-verbatim top-2 update (ascending index order -> strict > keeps lowest)
    // C/D layout: row = i*16 + quad*4 + r, col(code) = cbase + js*64 + j*16 + l15
#pragma unroll
    for (int i = 0; i < 4; ++i)
#pragma unroll
      for (int r = 0; r < 4; ++r)
#pragma unroll
        for (int j = 0; j < 4; ++j) {
          float s = acc[i][j][r];
          int c = cbase + js * 64 + j * 16 + l15;
          if (s > bv1[i][r]) {
            bv2[i][r] = bv1[i][r]; bi2[i][r] = bi1[i][r];
            bv1[i][r] = s; bi1[i][r] = c;
          } else if (s > bv2[i][r]) {
            bv2[i][r] = s; bi2[i][r] = c;
          }
        }
  }

  // R4-verbatim butterfly-merge top-2 across the 16 column-lanes of each quad
#pragma unroll
  for (int i = 0; i < 4; ++i)
#pragma unroll
    for (int r = 0; r < 4; ++r) {
      float a1 = bv1[i][r], a2 = bv2[i][r];
      int x1 = bi1[i][r], x2 = bi2[i][r];
#pragma unroll
      for (int d = 1; d < 16; d <<= 1) {
        float b1 = __shfl_xor(a1, d), b2 = __shfl_xor(a2, d);
        int y1 = __shfl_xor(x1, d), y2 = __shfl_xor(x2, d);
        bool bw = (b1 > a1) || (b1 == a1 && y1 < x1);
        float w1 = bw ? b1 : a1;  int wi = bw ? y1 : x1;
        float l1 = bw ? a1 : b1;  int li = bw ? x1 : y1;
        float s2 = bw ? b2 : a2;  int si = bw ? y2 : x2;
        bool t = (s2 > l1) || (s2 == l1 && si < li);
        a1 = w1; x1 = wi;
        a2 = t ? s2 : l1; x2 = t ? si : li;
      }
      bv1[i][r] = a1; bi1[i][r] = x1; bv2[i][r] = a2; bi2[i][r] = x2;
    }

  if (l15 == 0) {
#pragma unroll
    for (int i = 0; i < 4; ++i)
#pragma unroll
      for (int r = 0; r < 4; ++r) {
        const int rl = wm * 64 + i * 16 + quad * 4 + r;
        rv1[wn][rl] = bv1[i][r]; ri1[wn][rl] = bi1[i][r];
        rv2[wn][rl] = bv2[i][r]; ri2[wn][rl] = bi2[i][r];
      }
  }
  __syncthreads();
  if (tid < BM) {
    float a1 = rv1[0][tid], a2 = rv2[0][tid];
    int x1 = ri1[0][tid], x2 = ri2[0][tid];
    float b1 = rv1[1][tid], b2 = rv2[1][tid];
    int y1 = ri1[1][tid], y2 = ri2[1][tid];
    bool bw = (b1 > a1) || (b1 == a1 && y1 < x1);
    float w1 = bw ? b1 : a1;  int wi = bw ? y1 : x1;
    float l1 = bw ? a1 : b1;  int li = bw ? x1 : y1;
    float s2 = bw ? b2 : a2;  int si = bw ? y2 : x2;
    bool t = (s2 > l1) || (s2 == l1 && si < li);
    float m2 = t ? s2 : l1;  int mi2 = t ? si : li;
    const size_t o = (size_t)(row0 + tid) * (NSPLIT * 2) + split * 2;
    pv[o] = w1; pi[o] = wi;
    pv[o + 1] = m2; pi[o + 1] = mi2;
  }
}

__device__ double dot64(const float* __restrict__ a, const float* __restrict__ b) {
  double s0 = 0, s1 = 0, s2 = 0, s3 = 0;
#pragma unroll 4
  for (int t = 0; t < DIM; t += 4) {
    const float4 u = *(const float4*)(a + t);
    const float4 v = *(const float4*)(b + t);
    s0 += (double)u.x * v.x; s1 += (double)u.y * v.y;
    s2 += (double)u.z * v.z; s3 += (double)u.w * v.w;
  }
  return (s0 + s1) + (s2 + s3);
}

// R4-verbatim recheck: 128 candidates/row (64 splits x top-2), margin-flag,
// exact fp64 recheck, lowest-index tie-break, gather.
__global__ void recheck_gather(const float* __restrict__ pv, const int* __restrict__ pi,
                               const float* __restrict__ x, const float* __restrict__ cb,
                               float* __restrict__ out) {
  const int row = blockIdx.x;
  const int lane = threadIdx.x;   // 64 lanes, 2 candidates each (128 total)
  const size_t base = (size_t)row * (NSPLIT * 2);
  float v0 = pv[base + lane];      int c0 = pi[base + lane];
  float v1 = pv[base + 64 + lane]; int c1 = pi[base + 64 + lane];

  bool b = (v1 > v0) || (v1 == v0 && c1 < c0);
  float m1 = b ? v1 : v0; int mi1 = b ? c1 : c0;
#pragma unroll
  for (int d = 1; d < 64; d <<= 1) {
    float ov = __shfl_xor(m1, d);
    int oi = __shfl_xor(mi1, d);
    if (ov > m1 || (ov == m1 && oi < mi1)) { m1 = ov; mi1 = oi; }
  }

  const bool f0 = (v0 >= m1 - MARGIN);
  const bool f1 = (v1 >= m1 - MARGIN);
  const int nf = __popcll(__ballot(f0)) + __popcll(__ballot(f1));
  int winner;
  if (nf == 1) {
    winner = mi1;
  } else {
    const float* xr = x + (size_t)row * DIM;
    double e = -1.0e300; int ei = 0x7fffffff;
    if (f0) { e = dot64(xr, cb + (size_t)c0 * DIM); ei = c0; }
    if (f1) {
      double e2 = dot64(xr, cb + (size_t)c1 * DIM);
      if (e2 > e || (e2 == e && c1 < ei)) { e = e2; ei = c1; }
    }
#pragma unroll
    for (int d = 1; d < 64; d <<= 1) {
      double oe = __shfl_xor(e, d);
      int oi = __shfl_xor(ei, d);
      if (oe > e || (oe == e && oi < ei)) { e = oe; ei = oi; }
    }
    winner = ei;
  }

  const float4* src = (const float4*)(cb + (size_t)winner * DIM);
  float4* dst = (float4*)(out + (size_t)row * DIM);
  dst[lane] = src[lane];
  dst[lane + 64] = src[lane + 64];
}

extern "C" void kernel_launch(void* const* d_in, const int* in_sizes, int n_in,
                              void* d_out, int out_size, void* d_ws, size_t ws_size,
                              hipStream_t stream) {
  const float* x = (const float*)d_in[0];
  const float* cb = (const float*)d_in[1];
  float* out = (float*)d_out;

  // ws layout: x_fp8(4MB) cb_fp8(8MB) pv(4MB) pi(4MB)
  uint8_t* xq = (uint8_t*)d_ws;
  uint8_t* cq = xq + (size_t)M_ROWS * DIM;
  float* pv = (float*)(cq + (size_t)K_CODES * DIM);
  int* pi = (int*)(pv + (size_t)M_ROWS * NSPLIT * 2);

  cvt_fp8<<<(N4X + N4C + 255) / 256, 256, 0, stream>>>(x, cb, xq, cq);
  vq_argmax<<<dim3(M_ROWS / BM, NSPLIT), 256, 0, stream>>>(xq, cq, pv, pi);
  recheck_gather<<<M_ROWS, 64, 0, stream>>>(pv, pi, x, cb, out);
}

// Round 7
// 573.118 us; speedup vs baseline: 1.1709x; 1.1709x over previous
//
#include <hip/hip_runtime.h>
#include <hip/hip_bf16.h>
#include <stdint.h>

// VectorQuantization: out[n] = codebook[argmax_k dot(x[n], codebook[k])]
// (L2-normalize is a positive row-scalar -> argmax-invariant -> skipped)
//
// R7 = R6 with ONE change: __launch_bounds__(256,1).
// R6 post-mortem: compiler capped VGPR at 128 (aiming for 4 waves/SIMD under
// the (256,2) minimum) while live state needs ~208 -> ~80 regs spilled to
// scratch -> WRITE_SIZE 720 MB / FETCH 415 MB of pure spill traffic, MfmaUtil
// 5%, 550 us. (256,1) lifts the cap; expected ~210 VGPR, zero spill, HW
// occupancy 2 waves/SIMD (same as R4) with NO k-loop barriers.
//
// Validated-by-bench components (R4/R6, absmax 0.0): fp8 e4m3 conversion with
// x64 codebook prescale, mfma_scale_f32_16x16x128_f8f6f4 with unit e8m0
// scales, global->VGPR fragment loads, explicit (v,i) top-2 epilogue with
// lowest-index tie-break, NSPLIT=64 coverage + MARGIN=3.2 + fp64 recheck.

typedef float f32x4 __attribute__((ext_vector_type(4)));
typedef int int4v __attribute__((ext_vector_type(4)));
typedef int int8v __attribute__((ext_vector_type(8)));

#define M_ROWS 8192
#define DIM 512
#define K_CODES 16384
#define BM 128
#define NSPLIT 64
#define CPS (K_CODES / NSPLIT)      /* 256 codes per split */
#define NEG_INF (-3.402823466e+38f)
#define MARGIN 3.2f                 /* 0.05 in true sim scale (x64) */
#define CB_SCALE 64.0f
#define N4X (M_ROWS * DIM / 4)
#define N4C (K_CODES * DIM / 4)

// fused fp32 -> e4m3: blocks [0, N4X/256) convert x (scale 1), rest codebook (x64)
__global__ void cvt_fp8(const float* __restrict__ x, const float* __restrict__ cb,
                        uint8_t* __restrict__ xd, uint8_t* __restrict__ cd) {
  int i = blockIdx.x * 256 + threadIdx.x;
  const float* src;
  uint8_t* dst;
  float sc;
  if (i < N4X) {
    src = x; dst = xd; sc = 1.0f;
  } else {
    src = cb; dst = cd; sc = CB_SCALE; i -= N4X;
    if (i >= N4C) return;
  }
  const float4 v = reinterpret_cast<const float4*>(src)[i];
  int w = 0;
  w = __builtin_amdgcn_cvt_pk_fp8_f32(v.x * sc, v.y * sc, w, false);
  w = __builtin_amdgcn_cvt_pk_fp8_f32(v.z * sc, v.w * sc, w, true);
  reinterpret_cast<int*>(dst)[i] = w;
}

__device__ __forceinline__ int8v load32(const uint8_t* p) {
  int4v lo = *(const int4v*)p;
  int4v hi = *(const int4v*)(p + 16);
  return __builtin_shufflevector(lo, hi, 0, 1, 2, 3, 4, 5, 6, 7);
}

__global__ __launch_bounds__(256, 1) void vq_argmax(
    const uint8_t* __restrict__ xq, const uint8_t* __restrict__ cq,
    float* __restrict__ pv, int* __restrict__ pi) {
  __shared__ float rv1[2][BM], rv2[2][BM];     // tiny cross-wave merge scratch
  __shared__ int ri1[2][BM], ri2[2][BM];

  const int tid = threadIdx.x;
  const int w = tid >> 6, lane = tid & 63;
  const int wm = w & 1, wn = w >> 1;           // 2x2 wave grid: rows x codes
  const int l15 = lane & 15, quad = lane >> 4;
  const int row0 = blockIdx.x * BM;
  const int split = blockIdx.y;
  const int cbase = split * CPS + wn * 128;    // this wave's 128-code strip

  // per-lane fragment base pointers: 32 contiguous bytes at k = quad*32
  const uint8_t* abase = xq + (size_t)(row0 + wm * 64 + l15) * DIM + (quad << 5);
  const uint8_t* bbase = cq + (size_t)(cbase + l15) * DIM + (quad << 5);

  float bv1[4][4], bv2[4][4];
  int bi1[4][4], bi2[4][4];
#pragma unroll
  for (int i = 0; i < 4; ++i)
#pragma unroll
    for (int r = 0; r < 4; ++r) {
      bv1[i][r] = NEG_INF; bv2[i][r] = NEG_INF;
      bi1[i][r] = 0x7fffffff; bi2[i][r] = 0x7fffffff;
    }

#pragma unroll
  for (int js = 0; js < 2; ++js) {             // 64 codes per js-step per wave
    f32x4 acc[4][4];
#pragma unroll
    for (int i = 0; i < 4; ++i)
#pragma unroll
      for (int j = 0; j < 4; ++j) acc[i][j] = (f32x4){0.f, 0.f, 0.f, 0.f};

#pragma unroll
    for (int ks = 0; ks < 4; ++ks) {
      int8v A[4], B[4];
#pragma unroll
      for (int i = 0; i < 4; ++i)
        A[i] = load32(abase + (size_t)(i * 16) * DIM + ks * 128);
#pragma unroll
      for (int j = 0; j < 4; ++j)
        B[j] = load32(bbase + (size_t)(js * 64 + j * 16) * DIM + ks * 128);
#pragma unroll
      for (int i = 0; i < 4; ++i)
#pragma unroll
        for (int j = 0; j < 4; ++j)
          acc[i][j] = __builtin_amdgcn_mfma_scale_f32_16x16x128_f8f6f4(
              A[i], B[j], acc[i][j], 0 /*fp8*/, 0 /*fp8*/,
              0, 0x7F7F7F7F /*scaleA=1.0*/, 0, 0x7F7F7F7F /*scaleB=1.0*/);
    }

    // top-2 update (ascending index order -> strict > keeps lowest index)
    // C/D layout: row = i*16 + quad*4 + r, col(code) = cbase + js*64 + j*16 + l15
#pragma unroll
    for (int i = 0; i < 4; ++i)
#pragma unroll
      for (int r = 0; r < 4; ++r)
#pragma unroll
        for (int j = 0; j < 4; ++j) {
          float s = acc[i][j][r];
          int c = cbase + js * 64 + j * 16 + l15;
          if (s > bv1[i][r]) {
            bv2[i][r] = bv1[i][r]; bi2[i][r] = bi1[i][r];
            bv1[i][r] = s; bi1[i][r] = c;
          } else if (s > bv2[i][r]) {
            bv2[i][r] = s; bi2[i][r] = c;
          }
        }
  }

  // butterfly-merge top-2 across the 16 column-lanes of each quad
#pragma unroll
  for (int i = 0; i < 4; ++i)
#pragma unroll
    for (int r = 0; r < 4; ++r) {
      float a1 = bv1[i][r], a2 = bv2[i][r];
      int x1 = bi1[i][r], x2 = bi2[i][r];
#pragma unroll
      for (int d = 1; d < 16; d <<= 1) {
        float b1 = __shfl_xor(a1, d), b2 = __shfl_xor(a2, d);
        int y1 = __shfl_xor(x1, d), y2 = __shfl_xor(x2, d);
        bool bw = (b1 > a1) || (b1 == a1 && y1 < x1);
        float w1 = bw ? b1 : a1;  int wi = bw ? y1 : x1;
        float l1 = bw ? a1 : b1;  int li = bw ? x1 : y1;
        float s2 = bw ? b2 : a2;  int si = bw ? y2 : x2;
        bool t = (s2 > l1) || (s2 == l1 && si < li);
        a1 = w1; x1 = wi;
        a2 = t ? s2 : l1; x2 = t ? si : li;
      }
      bv1[i][r] = a1; bi1[i][r] = x1; bv2[i][r] = a2; bi2[i][r] = x2;
    }

  if (l15 == 0) {
#pragma unroll
    for (int i = 0; i < 4; ++i)
#pragma unroll
      for (int r = 0; r < 4; ++r) {
        const int rl = wm * 64 + i * 16 + quad * 4 + r;
        rv1[wn][rl] = bv1[i][r]; ri1[wn][rl] = bi1[i][r];
        rv2[wn][rl] = bv2[i][r]; ri2[wn][rl] = bi2[i][r];
      }
  }
  __syncthreads();
  if (tid < BM) {
    float a1 = rv1[0][tid], a2 = rv2[0][tid];
    int x1 = ri1[0][tid], x2 = ri2[0][tid];
    float b1 = rv1[1][tid], b2 = rv2[1][tid];
    int y1 = ri1[1][tid], y2 = ri2[1][tid];
    bool bw = (b1 > a1) || (b1 == a1 && y1 < x1);
    float w1 = bw ? b1 : a1;  int wi = bw ? y1 : x1;
    float l1 = bw ? a1 : b1;  int li = bw ? x1 : y1;
    float s2 = bw ? b2 : a2;  int si = bw ? y2 : x2;
    bool t = (s2 > l1) || (s2 == l1 && si < li);
    float m2 = t ? s2 : l1;  int mi2 = t ? si : li;
    const size_t o = (size_t)(row0 + tid) * (NSPLIT * 2) + split * 2;
    pv[o] = w1; pi[o] = wi;
    pv[o + 1] = m2; pi[o + 1] = mi2;
  }
}

__device__ double dot64(const float* __restrict__ a, const float* __restrict__ b) {
  double s0 = 0, s1 = 0, s2 = 0, s3 = 0;
#pragma unroll 4
  for (int t = 0; t < DIM; t += 4) {
    const float4 u = *(const float4*)(a + t);
    const float4 v = *(const float4*)(b + t);
    s0 += (double)u.x * v.x; s1 += (double)u.y * v.y;
    s2 += (double)u.z * v.z; s3 += (double)u.w * v.w;
  }
  return (s0 + s1) + (s2 + s3);
}

// recheck: 128 candidates/row (64 splits x top-2), margin-flag, exact fp64
// recheck, lowest-index tie-break, gather.
__global__ void recheck_gather(const float* __restrict__ pv, const int* __restrict__ pi,
                               const float* __restrict__ x, const float* __restrict__ cb,
                               float* __restrict__ out) {
  const int row = blockIdx.x;
  const int lane = threadIdx.x;   // 64 lanes, 2 candidates each (128 total)
  const size_t base = (size_t)row * (NSPLIT * 2);
  float v0 = pv[base + lane];      int c0 = pi[base + lane];
  float v1 = pv[base + 64 + lane]; int c1 = pi[base + 64 + lane];

  bool b = (v1 > v0) || (v1 == v0 && c1 < c0);
  float m1 = b ? v1 : v0; int mi1 = b ? c1 : c0;
#pragma unroll
  for (int d = 1; d < 64; d <<= 1) {
    float ov = __shfl_xor(m1, d);
    int oi = __shfl_xor(mi1, d);
    if (ov > m1 || (ov == m1 && oi < mi1)) { m1 = ov; mi1 = oi; }
  }

  const bool f0 = (v0 >= m1 - MARGIN);
  const bool f1 = (v1 >= m1 - MARGIN);
  const int nf = __popcll(__ballot(f0)) + __popcll(__ballot(f1));
  int winner;
  if (nf == 1) {
    winner = mi1;
  } else {
    const float* xr = x + (size_t)row * DIM;
    double e = -1.0e300; int ei = 0x7fffffff;
    if (f0) { e = dot64(xr, cb + (size_t)c0 * DIM); ei = c0; }
    if (f1) {
      double e2 = dot64(xr, cb + (size_t)c1 * DIM);
      if (e2 > e || (e2 == e && c1 < ei)) { e = e2; ei = c1; }
    }
#pragma unroll
    for (int d = 1; d < 64; d <<= 1) {
      double oe = __shfl_xor(e, d);
      int oi = __shfl_xor(ei, d);
      if (oe > e || (oe == e && oi < ei)) { e = oe; ei = oi; }
    }
    winner = ei;
  }

  const float4* src = (const float4*)(cb + (size_t)winner * DIM);
  float4* dst = (float4*)(out + (size_t)row * DIM);
  dst[lane] = src[lane];
  dst[lane + 64] = src[lane + 64];
}

extern "C" void kernel_launch(void* const* d_in, const int* in_sizes, int n_in,
                              void* d_out, int out_size, void* d_ws, size_t ws_size,
                              hipStream_t stream) {
  const float* x = (const float*)d_in[0];
  const float* cb = (const float*)d_in[1];
  float* out = (float*)d_out;

  // ws layout: x_fp8(4MB) cb_fp8(8MB) pv(4MB) pi(4MB)
  uint8_t* xq = (uint8_t*)d_ws;
  uint8_t* cq = xq + (size_t)M_ROWS * DIM;
  float* pv = (float*)(cq + (size_t)K_CODES * DIM);
  int* pi = (int*)(pv + (size_t)M_ROWS * NSPLIT * 2);

  cvt_fp8<<<(N4X + N4C + 255) / 256, 256, 0, stream>>>(x, cb, xq, cq);
  vq_argmax<<<dim3(M_ROWS / BM, NSPLIT), 256, 0, stream>>>(xq, cq, pv, pi);
  recheck_gather<<<M_ROWS, 64, 0, stream>>>(pv, pi, x, cb, out);
}

// Round 8
// 400.417 us; speedup vs baseline: 1.6759x; 1.4313x over previous
//
#include <hip/hip_runtime.h>
#include <hip/hip_bf16.h>
#include <stdint.h>

// VectorQuantization: out[n] = codebook[argmax_k dot(x[n], codebook[k])]
// (L2-normalize is a positive row-scalar -> argmax-invariant -> skipped)
//
// R8: hybrid barrier-light fp8 GEMM.
//  - R7 post-mortem: row-strided global fragment loads = 16 scattered cache
//    lines per instr -> L1-transaction-bound (~75k cyc/block); 268 total regs
//    -> 1 wave/SIMD. Fixes:
//  - B (codebook) PACKED INTO FRAGMENT ORDER at conversion: one fragment =
//    2 KB contiguous; wave loads it as 2x fully-coalesced 1 KB instructions.
//  - A (x) staged to LDS ONCE per block (32 KB tile + 4 KB scratch = R4's
//    validated 36 KB; R5's failed 67 KB avoided), R5-verified XOR swizzle,
//    no k-loop barriers. All 4 waves share A; each owns a 64-code strip.
//  - amdgpu_waves_per_eu(2,2): pin 2 waves/SIMD (256-reg cap), avoiding both
//    R6's heuristic spill-at-128 and R7's 1-wave residency.
//  - Candidate structure per (row, split) = top-2 of 256 codes == validated
//    R4/R6/R7 structure; recheck_gather verbatim.

typedef float f32x4 __attribute__((ext_vector_type(4)));
typedef int int4v __attribute__((ext_vector_type(4)));
typedef int int8v __attribute__((ext_vector_type(8)));

#define M_ROWS 8192
#define DIM 512
#define K_CODES 16384
#define BM 64                       /* rows per block (LDS A-tile = 32 KB) */
#define NSPLIT 64
#define CPS (K_CODES / NSPLIT)      /* 256 codes per split */
#define NEG_INF (-3.402823466e+38f)
#define MARGIN 3.2f                 /* 0.05 in true sim scale (x64) */
#define CB_SCALE 64.0f
#define N4X (M_ROWS * DIM / 4)
#define N4C (K_CODES * DIM / 4)

typedef __attribute__((address_space(1))) uint32_t as1_u32;
typedef __attribute__((address_space(3))) uint32_t as3_u32;

__device__ __forceinline__ void gll16(const void* g, void* l) {
  __builtin_amdgcn_global_load_lds((const as1_u32*)(uintptr_t)g,
                                   (as3_u32*)(uintptr_t)l, 16, 0, 0);
}

// fp32 -> e4m3. x: plain row-major (scale 1). codebook: x64 prescale, written
// in MFMA-fragment-packed order:
//   off(code n, k) = (n>>4)*8192 + (k>>7)*2048 + (((k>>5)&3)*16 + (n&15))*32
//                    + ((k>>4)&1)*16 + (k&15)
// so one (16-code, 128-k) fragment occupies 2048 contiguous bytes with
// lane l's 32 B at lane*32 (l&15 = code, l>>4 = 32-byte k-chunk).
__global__ void cvt_fp8(const float* __restrict__ x, const float* __restrict__ cb,
                        uint8_t* __restrict__ xd, uint8_t* __restrict__ cp) {
  int i = blockIdx.x * 256 + threadIdx.x;
  if (i < N4X) {
    const float4 v = reinterpret_cast<const float4*>(x)[i];
    int w = 0;
    w = __builtin_amdgcn_cvt_pk_fp8_f32(v.x, v.y, w, false);
    w = __builtin_amdgcn_cvt_pk_fp8_f32(v.z, v.w, w, true);
    reinterpret_cast<int*>(xd)[i] = w;
    return;
  }
  i -= N4X;
  if (i >= N4C) return;
  const float4 v = reinterpret_cast<const float4*>(cb)[i];
  int w = 0;
  w = __builtin_amdgcn_cvt_pk_fp8_f32(v.x * CB_SCALE, v.y * CB_SCALE, w, false);
  w = __builtin_amdgcn_cvt_pk_fp8_f32(v.z * CB_SCALE, v.w * CB_SCALE, w, true);
  const int n = i >> 7;            // code index (128 float4-groups per code)
  const int g = i & 127;           // float4-group within code, k0 = 4*g
  const size_t off = (size_t)(n >> 4) * 8192 + (size_t)(g >> 5) * 2048 +
                     (size_t)((((g >> 3) & 3) * 16 + (n & 15)) * 32) +
                     ((g >> 2) & 1) * 16 + (g & 3) * 4;
  *reinterpret_cast<int*>(cp + off) = w;
}

__global__ __launch_bounds__(256)
__attribute__((amdgpu_waves_per_eu(2, 2))) void vq_argmax(
    const uint8_t* __restrict__ xq, const uint8_t* __restrict__ cp,
    float* __restrict__ pv, int* __restrict__ pi) {
  // A tile: 64 rows x 512 B, swizzled: 16B-slot s holds chunk
  // kc = (cs&24)|((cs&7)^(row&7)) of row = s>>5  (R5-verified math)
  __shared__ __align__(16) uint8_t sxa[BM * DIM];   // 32 KB
  __shared__ float rv1[4][BM], rv2[4][BM];          // 4 KB merge scratch
  __shared__ int ri1[4][BM], ri2[4][BM];

  const int tid = threadIdx.x;
  const int w = tid >> 6, lane = tid & 63;
  const int l15 = lane & 15, quad = lane >> 4;
  const int row0 = blockIdx.x * BM;
  const int split = blockIdx.y;
  const int cbase = split * CPS + w * 64;      // this wave's 64-code strip

  // ---- stage A once: 32 KB = 8 rounds x 256 threads x 16B ----
#pragma unroll
  for (int r = 0; r < 8; ++r) {
    const int s = r * 256 + tid;               // LDS 16B-slot id
    const int row = s >> 5;                    // 32 chunks per 512B row
    const int cs = s & 31;
    const int kc = (cs & 24) | ((cs & 7) ^ (row & 7));
    const uint8_t* g = xq + (size_t)(row0 + row) * DIM + (kc << 4);
    uint8_t* l = sxa + ((size_t)(r * 256 + (tid & 192)) << 4);
    gll16((const void*)g, (void*)l);
  }
  __syncthreads();   // the ONLY pre-epilogue barrier

  // A-read swizzle: chunk c = ks*8 + 2q + h -> slot ks*8 + ((2q+h)^(l15&7))
  const int sw = l15 & 7;
  const int pa0 = (quad << 1) ^ sw;
  const int pa1 = pa0 ^ 1;                     // (2q+1)^sw since 2q is even

  // packed-B fragment base: code-tile t = split*16 + w*4 + j
  const uint8_t* bbase = cp + (size_t)(split * 16 + w * 4) * 8192 + (size_t)lane * 32;

  f32x4 acc[4][4];
#pragma unroll
  for (int i = 0; i < 4; ++i)
#pragma unroll
    for (int j = 0; j < 4; ++j) acc[i][j] = (f32x4){0.f, 0.f, 0.f, 0.f};

#pragma unroll
  for (int ks = 0; ks < 4; ++ks) {
    int8v A[4], B[4];
#pragma unroll
    for (int j = 0; j < 4; ++j) {
      const uint8_t* p = bbase + (size_t)j * 8192 + ks * 2048;
      int4v blo = *(const int4v*)p;
      int4v bhi = *(const int4v*)(p + 16);
      B[j] = __builtin_shufflevector(blo, bhi, 0, 1, 2, 3, 4, 5, 6, 7);
    }
#pragma unroll
    for (int i = 0; i < 4; ++i) {
      const int rb = (i * 16 + l15) * DIM + ks * 128;
      int4v alo = *(const int4v*)&sxa[rb + (pa0 << 4)];
      int4v ahi = *(const int4v*)&sxa[rb + (pa1 << 4)];
      A[i] = __builtin_shufflevector(alo, ahi, 0, 1, 2, 3, 4, 5, 6, 7);
    }
#pragma unroll
    for (int i = 0; i < 4; ++i)
#pragma unroll
      for (int j = 0; j < 4; ++j)
        acc[i][j] = __builtin_amdgcn_mfma_scale_f32_16x16x128_f8f6f4(
            A[i], B[j], acc[i][j], 0 /*fp8*/, 0 /*fp8*/,
            0, 0x7F7F7F7F /*scaleA=1.0*/, 0, 0x7F7F7F7F /*scaleB=1.0*/);
  }

  // top-2 over this wave's 64 codes (ascending index -> strict > keeps lowest)
  // C/D layout: row = i*16 + quad*4 + r, col(code) = cbase + j*16 + l15
  float bv1[4][4], bv2[4][4];
  int bi1[4][4], bi2[4][4];
#pragma unroll
  for (int i = 0; i < 4; ++i)
#pragma unroll
    for (int r = 0; r < 4; ++r) {
      bv1[i][r] = NEG_INF; bv2[i][r] = NEG_INF;
      bi1[i][r] = 0x7fffffff; bi2[i][r] = 0x7fffffff;
#pragma unroll
      for (int j = 0; j < 4; ++j) {
        float s = acc[i][j][r];
        int c = cbase + j * 16 + l15;
        if (s > bv1[i][r]) {
          bv2[i][r] = bv1[i][r]; bi2[i][r] = bi1[i][r];
          bv1[i][r] = s; bi1[i][r] = c;
        } else if (s > bv2[i][r]) {
          bv2[i][r] = s; bi2[i][r] = c;
        }
      }
    }

  // butterfly-merge top-2 across the 16 column-lanes of each quad
#pragma unroll
  for (int i = 0; i < 4; ++i)
#pragma unroll
    for (int r = 0; r < 4; ++r) {
      float a1 = bv1[i][r], a2 = bv2[i][r];
      int x1 = bi1[i][r], x2 = bi2[i][r];
#pragma unroll
      for (int d = 1; d < 16; d <<= 1) {
        float b1 = __shfl_xor(a1, d), b2 = __shfl_xor(a2, d);
        int y1 = __shfl_xor(x1, d), y2 = __shfl_xor(x2, d);
        bool bw = (b1 > a1) || (b1 == a1 && y1 < x1);
        float w1 = bw ? b1 : a1;  int wi = bw ? y1 : x1;
        float l1 = bw ? a1 : b1;  int li = bw ? x1 : y1;
        float s2 = bw ? b2 : a2;  int si = bw ? y2 : x2;
        bool t = (s2 > l1) || (s2 == l1 && si < li);
        a1 = w1; x1 = wi;
        a2 = t ? s2 : l1; x2 = t ? si : li;
      }
      bv1[i][r] = a1; bi1[i][r] = x1; bv2[i][r] = a2; bi2[i][r] = x2;
    }

  if (l15 == 0) {
#pragma unroll
    for (int i = 0; i < 4; ++i)
#pragma unroll
      for (int r = 0; r < 4; ++r) {
        const int rl = i * 16 + quad * 4 + r;
        rv1[w][rl] = bv1[i][r]; ri1[w][rl] = bi1[i][r];
        rv2[w][rl] = bv2[i][r]; ri2[w][rl] = bi2[i][r];
      }
  }
  __syncthreads();
  if (tid < BM) {
    // merge 4 waves' top-2 -> block top-2 (codes ordered by wave strip)
    float m1 = rv1[0][tid], m2 = rv2[0][tid];
    int j1 = ri1[0][tid], j2 = ri2[0][tid];
#pragma unroll
    for (int ww = 1; ww < 4; ++ww) {
      float b1 = rv1[ww][tid], b2 = rv2[ww][tid];
      int y1 = ri1[ww][tid], y2 = ri2[ww][tid];
      bool bw = (b1 > m1) || (b1 == m1 && y1 < j1);
      float w1 = bw ? b1 : m1;  int wi = bw ? y1 : j1;
      float l1 = bw ? m1 : b1;  int li = bw ? j1 : y1;
      float s2 = bw ? b2 : m2;  int si = bw ? y2 : j2;
      bool t = (s2 > l1) || (s2 == l1 && si < li);
      m1 = w1; j1 = wi;
      m2 = t ? s2 : l1; j2 = t ? si : li;
    }
    const size_t o = (size_t)(row0 + tid) * (NSPLIT * 2) + split * 2;
    pv[o] = m1; pi[o] = j1;
    pv[o + 1] = m2; pi[o + 1] = j2;
  }
}

__device__ double dot64(const float* __restrict__ a, const float* __restrict__ b) {
  double s0 = 0, s1 = 0, s2 = 0, s3 = 0;
#pragma unroll 4
  for (int t = 0; t < DIM; t += 4) {
    const float4 u = *(const float4*)(a + t);
    const float4 v = *(const float4*)(b + t);
    s0 += (double)u.x * v.x; s1 += (double)u.y * v.y;
    s2 += (double)u.z * v.z; s3 += (double)u.w * v.w;
  }
  return (s0 + s1) + (s2 + s3);
}

// R4-verbatim recheck: 128 candidates/row (64 splits x top-2), margin-flag,
// exact fp64 recheck, lowest-index tie-break, gather.
__global__ void recheck_gather(const float* __restrict__ pv, const int* __restrict__ pi,
                               const float* __restrict__ x, const float* __restrict__ cb,
                               float* __restrict__ out) {
  const int row = blockIdx.x;
  const int lane = threadIdx.x;   // 64 lanes, 2 candidates each (128 total)
  const size_t base = (size_t)row * (NSPLIT * 2);
  float v0 = pv[base + lane];      int c0 = pi[base + lane];
  float v1 = pv[base + 64 + lane]; int c1 = pi[base + 64 + lane];

  bool b = (v1 > v0) || (v1 == v0 && c1 < c0);
  float m1 = b ? v1 : v0; int mi1 = b ? c1 : c0;
#pragma unroll
  for (int d = 1; d < 64; d <<= 1) {
    float ov = __shfl_xor(m1, d);
    int oi = __shfl_xor(mi1, d);
    if (ov > m1 || (ov == m1 && oi < mi1)) { m1 = ov; mi1 = oi; }
  }

  const bool f0 = (v0 >= m1 - MARGIN);
  const bool f1 = (v1 >= m1 - MARGIN);
  const int nf = __popcll(__ballot(f0)) + __popcll(__ballot(f1));
  int winner;
  if (nf == 1) {
    winner = mi1;
  } else {
    const float* xr = x + (size_t)row * DIM;
    double e = -1.0e300; int ei = 0x7fffffff;
    if (f0) { e = dot64(xr, cb + (size_t)c0 * DIM); ei = c0; }
    if (f1) {
      double e2 = dot64(xr, cb + (size_t)c1 * DIM);
      if (e2 > e || (e2 == e && c1 < ei)) { e = e2; ei = c1; }
    }
#pragma unroll
    for (int d = 1; d < 64; d <<= 1) {
      double oe = __shfl_xor(e, d);
      int oi = __shfl_xor(ei, d);
      if (oe > e || (oe == e && oi < ei)) { e = oe; ei = oi; }
    }
    winner = ei;
  }

  const float4* src = (const float4*)(cb + (size_t)winner * DIM);
  float4* dst = (float4*)(out + (size_t)row * DIM);
  dst[lane] = src[lane];
  dst[lane + 64] = src[lane + 64];
}

extern "C" void kernel_launch(void* const* d_in, const int* in_sizes, int n_in,
                              void* d_out, int out_size, void* d_ws, size_t ws_size,
                              hipStream_t stream) {
  const float* x = (const float*)d_in[0];
  const float* cb = (const float*)d_in[1];
  float* out = (float*)d_out;

  // ws layout: x_fp8(4MB) cb_fp8_packed(8MB) pv(4MB) pi(4MB)
  uint8_t* xq = (uint8_t*)d_ws;
  uint8_t* cp = xq + (size_t)M_ROWS * DIM;
  float* pv = (float*)(cp + (size_t)K_CODES * DIM);
  int* pi = (int*)(pv + (size_t)M_ROWS * NSPLIT * 2);

  cvt_fp8<<<(N4X + N4C + 255) / 256, 256, 0, stream>>>(x, cb, xq, cp);
  vq_argmax<<<dim3(M_ROWS / BM, NSPLIT), 256, 0, stream>>>(xq, cp, pv, pi);
  recheck_gather<<<M_ROWS, 64, 0, stream>>>(pv, pi, x, cb, out);
}